// Round 2
// baseline (465.529 us; speedup 1.0000x reference)
//
#include <hip/hip_runtime.h>

// CRF loss: sum_b(forward_score[b] - gold_score[b]).  B=512, T=1024, L=32.
//
// Forward alg in exp domain: q' = diag(exp(feat_t)) * E * q, E = exp(trans).
// R2: broadcast of q across 32 states via v_readlane -> SGPRs (no LDS in the
// recurrence loop). Renorm EVERY step: s_max_u32 over the 32 broadcast bit
// patterns (positive floats => integer compare is float compare) runs on the
// scalar pipe concurrently with the 32 v_fmac; exact 2^-e scale, C in SGPR.
// Labels ride the vmem path (lane-replicated load + readlane) so no smem/lds
// lgkm waits exist inside the loop. Gold transition score is recurrence-free
// and moves to its own parallel kernel.

#define TT 1024
#define LL 32
#define BB 512

__global__ __launch_bounds__(64, 1) void crf_forward_kernel(
    const float* __restrict__ emission,    // [B, T, L]
    const int*   __restrict__ label_ids,   // [B, T]
    const float* __restrict__ transitions, // [L, L]
    float*       __restrict__ pf_out)      // [B] forward - emit_gold
{
    __shared__ __align__(16) float shT[LL * LL];

    const int lane = threadIdx.x;   // 0..63
    const int j    = lane & 31;     // state (duplicated across wave halves)
    const int b    = blockIdx.x;

    // ---- stage transitions once (pre-loop; LDS never touched again) ----
    {
        const float4* g4 = (const float4*)transitions;
        float4* s4 = (float4*)shT;
#pragma unroll
        for (int m = 0; m < 4; ++m) s4[lane + 64 * m] = g4[lane + 64 * m];
    }
    asm volatile("s_waitcnt lgkmcnt(0)" ::: "memory");
    __builtin_amdgcn_wave_barrier();

    float E[32];
#pragma unroll
    for (int i = 0; i < 32; ++i) E[i] = __expf(shT[j * 32 + i]);
    const float Eend = __expf(shT[1 * 32 + j]);   // exp(trans[END][j])

    const float* emB  = emission + (size_t)b * TT * LL + j;
    const int*   labB = label_ids + b * TT;

    // emission prefetch ring (vmem, depth 8)
    float ring[8];
#pragma unroll
    for (int s = 0; s < 8; ++s) ring[s] = emB[s * LL];

    // labels: lane-replicated vector loads, double-buffered one 4-block ahead
    int labv_cur = labB[0 + (lane & 3)];
    int labv_pf  = labB[4 + (lane & 3)];

    float q = (j == 0) ? 1.0f : 0.0f;   // exp(alpha0) one-hot at SOS
    int   C = 0;                        // power-of-2 scale accumulator (SGPR)
    float emit_acc = 0.0f;

    float featc = ring[0];
    float fexpc = __expf(featc);

    for (int t0 = 0; t0 < TT; t0 += 4) {
#pragma unroll
        for (int s = 0; s < 4; ++s) {
            const int t = t0 + s;

            // ---- broadcast q -> 32 SGPRs; scalar-pipe max in parallel ----
            float qs[32];
            unsigned int mu = 0u;
#pragma unroll
            for (int i = 0; i < 32; ++i) {
                int bi = __builtin_amdgcn_readlane(__float_as_int(q), i);
                qs[i] = __int_as_float(bi);
                unsigned int u = (unsigned int)bi;
                mu = (u > mu) ? u : mu;     // positive floats: int max == fmax
            }

            // ---- dot: 32 fmac with SGPR broadcast operands, 4 chains ----
            float a0 = 0.f, a1 = 0.f, a2 = 0.f, a3 = 0.f;
#pragma unroll
            for (int m = 0; m < 8; ++m) {
                a0 = fmaf(E[4 * m + 0], qs[4 * m + 0], a0);
                a1 = fmaf(E[4 * m + 1], qs[4 * m + 1], a1);
                a2 = fmaf(E[4 * m + 2], qs[4 * m + 2], a2);
                a3 = fmaf(E[4 * m + 3], qs[4 * m + 3], a3);
            }
            float sdot = (a0 + a1) + (a2 + a3);

            // ---- exact power-of-2 renorm (every step; scalar side ops) ----
            int e = (int)(mu >> 23) - 127;
            float scale = __int_as_float((127 - e) << 23);   // 2^-e exact
            C += e;
            float fs = fexpc * scale;     // off critical path vs fmac stream
            q = sdot * fs;

            // ---- gold emission gather (uniform label via readlane) ----
            int lab = __builtin_amdgcn_readlane(labv_cur, s);
            emit_acc += (j == lab) ? featc : 0.0f;

            // ---- advance prefetch pipeline ----
            int tp = t + 8; if (tp > TT - 1) tp = TT - 1;
            ring[t & 7] = emB[tp * LL];
            featc = ring[(t + 1) & 7];
            fexpc = __expf(featc);
        }
        // rotate label buffers; prefetch block t0+8 (consumed at t0+4... one ahead)
        labv_cur = labv_pf;
        int off = t0 + 8; if (off > TT - 4) off = TT - 4;
        labv_pf = labB[off + (lane & 3)];
    }

    // ---- forward score ----
    float v = q * Eend;
#pragma unroll
    for (int m = 16; m >= 1; m >>= 1) v += __shfl_xor(v, m, 32);
    float fwd = __logf(v) + (float)C * 0.69314718055994531f;

#pragma unroll
    for (int m = 16; m >= 1; m >>= 1) emit_acc += __shfl_xor(emit_acc, m, 32);

    if (threadIdx.x == 0) pf_out[b] = fwd - emit_acc;
}

// Gold transition score: no recurrence -> fully parallel.
__global__ __launch_bounds__(256) void crf_gold_trans_kernel(
    const int* __restrict__ label_ids, const float* __restrict__ transitions,
    float* __restrict__ gt)
{
    __shared__ __align__(16) float shT[LL * LL];
    __shared__ float part[4];
    const int tid = threadIdx.x, b = blockIdx.x;

    ((float4*)shT)[tid] = ((const float4*)transitions)[tid];
    __syncthreads();

    const int* labB = label_ids + b * TT;
    int4 L = ((const int4*)labB)[tid];
    int  pv = (tid == 0) ? 0 : labB[4 * tid - 1];   // prev label (SOS at t=0)

    float s = shT[L.x * 32 + pv]  + shT[L.y * 32 + L.x]
            + shT[L.z * 32 + L.y] + shT[L.w * 32 + L.z];
    if (tid == 255) s += shT[1 * 32 + L.w];         // trans[END, last]

#pragma unroll
    for (int m = 32; m >= 1; m >>= 1) s += __shfl_xor(s, m, 64);
    if ((tid & 63) == 0) part[tid >> 6] = s;
    __syncthreads();
    if (tid == 0) gt[b] = (part[0] + part[1]) + (part[2] + part[3]);
}

__global__ __launch_bounds__(256) void crf_reduce_kernel(
    const float* __restrict__ pf, const float* __restrict__ gt,
    float* __restrict__ out)
{
    const int tid = threadIdx.x;
    float v = (pf[tid] - gt[tid]) + (pf[tid + 256] - gt[tid + 256]);
#pragma unroll
    for (int m = 32; m >= 1; m >>= 1) v += __shfl_xor(v, m, 64);
    __shared__ float sacc[4];
    if ((tid & 63) == 0) sacc[tid >> 6] = v;
    __syncthreads();
    if (tid == 0) out[0] = (sacc[0] + sacc[1]) + (sacc[2] + sacc[3]);
}

extern "C" void kernel_launch(void* const* d_in, const int* in_sizes, int n_in,
                              void* d_out, int out_size, void* d_ws, size_t ws_size,
                              hipStream_t stream)
{
    const float* emission    = (const float*)d_in[0];
    const int*   label_ids   = (const int*)d_in[1];
    const float* transitions = (const float*)d_in[2];
    float* pf = (float*)d_ws;            // [512]
    float* gt = pf + BB;                 // [512]
    float* out = (float*)d_out;

    crf_forward_kernel<<<BB, 64, 0, stream>>>(emission, label_ids, transitions, pf);
    crf_gold_trans_kernel<<<BB, 256, 0, stream>>>(label_ids, transitions, gt);
    crf_reduce_kernel<<<1, 256, 0, stream>>>(pf, gt, out);
}

// Round 3
// 302.364 us; speedup vs baseline: 1.5396x; 1.5396x over previous
//
#include <hip/hip_runtime.h>

// CRF loss: sum_b(forward_score[b] - gold_score[b]).  B=512, T=1024, L=32.
//
// Exp-domain forward alg: q' = diag(exp(feat_t)) * E * q, E = exp(trans).
// R3: systolic matvec via DPP wave_ror:1 — lane j accumulates its own dot
// product while q rotates past (32 dpp + 32 fmac, 4 round-robin accs).
// Batch duplicated in both wave halves so wave_ror1 == rotate mod 32.
// Ep[k] permutation derived at init by rotating an index vector with the
// SAME dpp op -> correct for either rotation direction.
// Renorm: deferred uniform 2^-e scale from exponent of readlane(q,2)
// (state 2: row SOS of E is all-zero so q[0]==0; col END is zero), folded
// into next step's fexp; exact power-of-2, C in sgpr, last e un-counted.
// Gold trans score in preamble, gold emission in-loop, one atomicAdd out.

#define TT 1024
#define LL 32
#define BB 512

__device__ __forceinline__ int rot_i(int x) {
    return __builtin_amdgcn_update_dpp(0, x, 0x13C, 0xF, 0xF, false); // wave_ror:1
}
__device__ __forceinline__ float rot_f(float x) {
    return __int_as_float(rot_i(__float_as_int(x)));
}

__global__ __launch_bounds__(64, 1) void crf_forward_kernel(
    const float* __restrict__ emission,    // [B, T, L]
    const int*   __restrict__ label_ids,   // [B, T]
    const float* __restrict__ transitions, // [L, L]
    float*       __restrict__ out)         // [1], pre-zeroed
{
    __shared__ __align__(16) float shT[LL * LL];

    const int lane = threadIdx.x;   // 0..63, single wave per block
    const int j    = lane & 31;     // state (duplicated across halves)
    const int b    = blockIdx.x;

    // ---- stage transitions (LDS used only in pre/postamble) ----
    {
        const float4* g4 = (const float4*)transitions;
        float4* s4 = (float4*)shT;
#pragma unroll
        for (int m = 0; m < 4; ++m) s4[lane + 64 * m] = g4[lane + 64 * m];
    }
    asm volatile("s_waitcnt lgkmcnt(0)" ::: "memory");
    __builtin_amdgcn_wave_barrier();

    const int* labB = label_ids + b * TT;

    // ---- gold transition score (recurrence-free, folded into preamble) ----
    float tgold = 0.0f;
#pragma unroll
    for (int it = 0; it < 16; ++it) {
        int t = lane + 64 * it;
        int l1 = labB[t];
        int l0 = (t == 0) ? 0 : labB[t - 1];          // SOS before t=0
        tgold += shT[(l1 << 5) + l0];
        if (t == TT - 1) tgold += shT[32 + l1];       // trans[END=1, last]
    }
#pragma unroll
    for (int m = 32; m >= 1; m >>= 1) tgold += __shfl_xor(tgold, m, 64);

    // ---- Ep[k] = E[j][sigma_k(lane)&31], sigma = the dpp rotation itself ----
    float Ep[32];
    {
        int idx = lane;
#pragma unroll
        for (int k = 0; k < 32; ++k) {
            Ep[k] = __expf(shT[(j << 5) + (idx & 31)]);
            idx = rot_i(idx);
        }
    }
    const float Eend = __expf(shT[32 + j]);           // exp(trans[END][j])

    const float* emB = emission + (size_t)b * TT * LL + j;

    // ---- prefetch rings (emission per-lane; labels broadcast) ----
    float ring[8];
    int   lring[8];
#pragma unroll
    for (int s = 0; s < 8; ++s) { ring[s] = emB[s * LL]; lring[s] = labB[s]; }

    float q = (j == 0) ? 1.0f : 0.0f;                 // exp(alpha0), one-hot SOS
    int   C = 0, laste = 0;
    float emit_acc = 0.0f;
    float featc = ring[0];
    int   labc  = lring[0];
    float fs    = __expf(featc);                      // fexp * pending-scale

    for (int t0 = 0; t0 < TT; t0 += 8) {
#pragma unroll
        for (int s = 0; s < 8; ++s) {
            const int t = t0 + s;

            // ---- systolic dot: q rotates past every lane ----
            float r = q;
            float a0 = 0.f, a1 = 0.f, a2 = 0.f, a3 = 0.f;
#pragma unroll
            for (int m = 0; m < 8; ++m) {
                a0 = fmaf(Ep[4 * m + 0], r, a0); r = rot_f(r);
                a1 = fmaf(Ep[4 * m + 1], r, a1); r = rot_f(r);
                a2 = fmaf(Ep[4 * m + 2], r, a2); r = rot_f(r);
                if (m < 7) { a3 = fmaf(Ep[4 * m + 3], r, a3); r = rot_f(r); }
                else       { a3 = fmaf(Ep[4 * m + 3], r, a3); }
            }
            q = ((a0 + a1) + (a2 + a3)) * fs;

            // ---- deferred exact renorm: exponent of q[2] (always > 0) ----
            int qb = __builtin_amdgcn_readlane(__float_as_int(q), 2);
            laste = ((qb >> 23) & 0xff) - 127;
            C += laste;
            float scale = __int_as_float((127 - laste) << 23);   // 2^-e exact

            // ---- gold emission gather + stream advance (off-chain) ----
            emit_acc += (j == labc) ? featc : 0.0f;
            float featn = ring[(t + 1) & 7];
            fs   = __expf(featn) * scale;
            featc = featn;
            labc  = lring[(t + 1) & 7];
            int tp = t + 8; if (tp > TT - 1) tp = TT - 1;
            ring[t & 7]  = emB[tp * LL];
            lring[t & 7] = labB[tp];
        }
    }

    // ---- forward score: last measured e was never applied -> C - laste ----
    float v = q * Eend;
#pragma unroll
    for (int m = 16; m >= 1; m >>= 1) v += __shfl_xor(v, m, 32);
    float fwd = __logf(v) + (float)(C - laste) * 0.69314718055994531f;

#pragma unroll
    for (int m = 16; m >= 1; m >>= 1) emit_acc += __shfl_xor(emit_acc, m, 32);

    if (lane == 0) atomicAdd(out, fwd - emit_acc - tgold);
}

extern "C" void kernel_launch(void* const* d_in, const int* in_sizes, int n_in,
                              void* d_out, int out_size, void* d_ws, size_t ws_size,
                              hipStream_t stream)
{
    const float* emission    = (const float*)d_in[0];
    const int*   label_ids   = (const int*)d_in[1];
    const float* transitions = (const float*)d_in[2];
    float* out = (float*)d_out;

    hipMemsetAsync(out, 0, sizeof(float), stream);
    crf_forward_kernel<<<BB, 64, 0, stream>>>(emission, label_ids, transitions, out);
}

// Round 4
// 199.946 us; speedup vs baseline: 2.3283x; 1.5122x over previous
//
#include <hip/hip_runtime.h>

// CRF loss: sum_b(forward_score[b] - gold_score[b]).  B=512, T=1024, L=32.
//
// R4: chunked matrix-product scan. q_{t+1} = (D_t E) q_t is linear, so split
// T into NC=8 chunks of CL=128; each wave computes its chunk's full 32x32
// product M_c = prod(D_t E) via M <- (D_t E) M = 2 chained mfma_32x32x16_bf16
// per step. 4096 independent chains (4 waves/SIMD) -> throughput-bound.
// D_t folds into the A operand (A row m = lane&31 = per-lane emission load).
// C/D-layout -> B-layout fixup: 16 ds_bpermute half-swaps + 16 cndmask.
// Renorm: exponent proxy readlane(acc[2],0) (row2/col0; SOS row & END col of
// M are structurally zero), exact 2^-e folded into next step's fexp.
// Combine kernel: per batch, 8 matvecs over stored chunk matrices + scales,
// plus gold scores; atomicAdd the loss.

typedef float  f32x16 __attribute__((ext_vector_type(16)));
typedef short  s16x8  __attribute__((ext_vector_type(8)));

#define TT 1024
#define LL 32
#define BB 512
#define NC 8
#define CL 128

union Frag { s16x8 v; unsigned u[4]; };

// pack two f32 -> one VGPR of 2 bf16 (truncation; bias ~ -2^-9 rel, harmless here)
__device__ __forceinline__ unsigned pack_bf16(float lo, float hi) {
    return __builtin_amdgcn_perm(__float_as_uint(hi), __float_as_uint(lo), 0x07060302u);
}

__global__ __launch_bounds__(64, 4) void crf_chunk_kernel(
    const float* __restrict__ emission,    // [B, T, L]
    const int*   __restrict__ label_ids,   // [B, T]
    const float* __restrict__ transitions, // [L, L]
    unsigned short* __restrict__ wsM,      // [B*NC][32][32] bf16 (row-major)
    int*   __restrict__ wsC,               // [B*NC] applied log2 scales
    float* __restrict__ wsE)               // [B*NC] gold-emit partials
{
    const int lane = threadIdx.x;
    const int j = lane & 31;               // A row m / B,D col n
    const int h = lane >> 5;               // k-half
    const int w = blockIdx.x;              // chunk id
    const int b = w >> 3, c = w & 7;
    const int t0 = c * CL;

    // E fragments (fp32): A0 needs E[j][8h+i], A1 needs E[j][16+8h+i]
    const float* trow = transitions + j * 32;
    float E0[8], E1[8];
#pragma unroll
    for (int i = 0; i < 8; ++i) {
        E0[i] = __expf(trow[8 * h + i]);
        E1[i] = __expf(trow[16 + 8 * h + i]);
    }

    const float* emB  = emission + ((size_t)b * TT + t0) * LL + j;
    const int*   labB = label_ids + b * TT + t0;
    const int swaddr = (lane ^ 32) << 2;   // ds_bpermute: half-swap

    // B operands start as identity (bf16 1.0 = 0x3F80)
    Frag B0, B1;
#pragma unroll
    for (int i = 0; i < 8; ++i) {
        B0.v[i] = (short)((8 * h + i == j) ? 0x3F80 : 0);
        B1.v[i] = (short)((16 + 8 * h + i == j) ? 0x3F80 : 0);
    }

    f32x16 zc, acc;
#pragma unroll
    for (int i = 0; i < 16; ++i) zc[i] = 0.0f;

    // emission prefetch ring
    float ring[8];
#pragma unroll
    for (int s = 0; s < 8; ++s) ring[s] = emB[s * LL];

    float sc = 1.0f;                       // pending 2^-e (wave-uniform)
    int   Cap = 0, e = 0;
    float emit = 0.0f;

#pragma unroll 8
    for (int s = 0; s < CL; ++s) {
        float feat = ring[s & 7];
        int lab = labB[s];                               // uniform -> s_load
        emit += (j == lab) ? feat : 0.0f;
        float fs = __expf(feat) * sc;

        // A = (2^-e * D_t) E rows, bf16
        Frag A0, A1;
#pragma unroll
        for (int p = 0; p < 4; ++p) {
            A0.u[p] = pack_bf16(fs * E0[2 * p], fs * E0[2 * p + 1]);
            A1.u[p] = pack_bf16(fs * E1[2 * p], fs * E1[2 * p + 1]);
        }

        acc = __builtin_amdgcn_mfma_f32_32x32x16_bf16(A0.v, B0.v, zc, 0, 0, 0);
        acc = __builtin_amdgcn_mfma_f32_32x32x16_bf16(A1.v, B1.v, acc, 0, 0, 0);

        // renorm proxy: row 2, col 0  (reg 2, lane 0)
        int pb = __builtin_amdgcn_readlane(__float_as_int(acc[2]), 0);
        e = ((pb >> 23) & 0xff) - 127;
        Cap += e;
        sc = __int_as_float((127 - e) << 23);            // exact 2^-e

        // refill ring (clamped inside this chunk's batch)
        int nf = s + 8; nf = (nf < CL) ? nf : (CL - 1);
        ring[s & 7] = emB[nf * LL];

        // D-layout -> next B-layout: half-swap + select
        float sw[16];
#pragma unroll
        for (int r = 0; r < 16; ++r)
            sw[r] = __int_as_float(
                __builtin_amdgcn_ds_bpermute(swaddr, __float_as_int(acc[r])));
        float b0v[8], b1v[8];
#pragma unroll
        for (int i = 0; i < 4; ++i) {
            b0v[i]     = h ? sw[4 + i]   : acc[i];
            b0v[4 + i] = h ? acc[4 + i]  : sw[i];
            b1v[i]     = h ? sw[12 + i]  : acc[8 + i];
            b1v[4 + i] = h ? acc[12 + i] : sw[8 + i];
        }
#pragma unroll
        for (int p = 0; p < 4; ++p) {
            B0.u[p] = pack_bf16(b0v[2 * p], b0v[2 * p + 1]);
            B1.u[p] = pack_bf16(b1v[2 * p], b1v[2 * p + 1]);
        }
    }
    Cap -= e;                              // last measured e never applied

    // store M_c (bf16 row-major); lane holds col j, rows r(reg,h)
    unsigned short* Mout = wsM + ((size_t)w << 10);
#pragma unroll
    for (int r = 0; r < 16; ++r) {
        int row = (r & 3) + 8 * (r >> 2) + 4 * h;
        Mout[row * 32 + j] = (unsigned short)(__float_as_uint(acc[r]) >> 16);
    }
    if (lane == 0) wsC[w] = Cap;
#pragma unroll
    for (int m = 16; m >= 1; m >>= 1) emit += __shfl_xor(emit, m, 32);
    if (lane == 0) wsE[w] = emit;
}

__global__ __launch_bounds__(64, 1) void crf_combine_kernel(
    const int*   __restrict__ label_ids,
    const float* __restrict__ transitions,
    const unsigned short* __restrict__ wsM,
    const int*   __restrict__ wsC,
    const float* __restrict__ wsE,
    float* __restrict__ out)               // [1], pre-zeroed
{
    __shared__ __align__(16) float shT[LL * LL];
    __shared__ __align__(16) float shQ[64];

    const int lane = threadIdx.x;
    const int j = lane & 31;
    const int h = lane >> 5;
    const int b = blockIdx.x;

    {
        const float4* g4 = (const float4*)transitions;
        float4* s4 = (float4*)shT;
#pragma unroll
        for (int m = 0; m < 4; ++m) s4[lane + 64 * m] = g4[lane + 64 * m];
    }
    __syncthreads();

    // gold transition score (verified R3 code)
    const int* labB = label_ids + b * TT;
    float tgold = 0.0f;
#pragma unroll
    for (int it = 0; it < 16; ++it) {
        int t = lane + 64 * it;
        int l1 = labB[t];
        int l0 = (t == 0) ? 0 : labB[t - 1];
        tgold += shT[(l1 << 5) + l0];
        if (t == TT - 1) tgold += shT[32 + l1];          // trans[END, last]
    }
#pragma unroll
    for (int m = 32; m >= 1; m >>= 1) tgold += __shfl_xor(tgold, m, 64);

    const float Eend = __expf(shT[32 + j]);              // exp(trans[END][j])

    float q = (j == 0) ? 1.0f : 0.0f;                    // exp(alpha0), SOS
    int   Cq = 0;
    float emitT = 0.0f;

    for (int c = 0; c < NC; ++c) {
        const unsigned short* Mrow = wsM + (((size_t)(b * NC + c)) << 10) + j * 32;
        uint4 mA = ((const uint4*)Mrow)[0];
        uint4 mB = ((const uint4*)Mrow)[1];
        unsigned mu[8] = {mA.x, mA.y, mA.z, mA.w, mB.x, mB.y, mB.z, mB.w};

        shQ[lane] = q;
        __syncthreads();
        float qn = 0.0f;
#pragma unroll
        for (int p = 0; p < 8; ++p) {
            float mlo = __uint_as_float(mu[p] << 16);
            float mhi = __uint_as_float(mu[p] & 0xFFFF0000u);
            qn = fmaf(mlo, shQ[h * 32 + 2 * p], qn);
            qn = fmaf(mhi, shQ[h * 32 + 2 * p + 1], qn);
        }
        __syncthreads();

        int pb = __builtin_amdgcn_readlane(__float_as_int(qn), 2);
        int e = ((pb >> 23) & 0xff) - 127;
        qn *= __int_as_float((127 - e) << 23);           // exact 2^-e
        Cq += e + wsC[b * NC + c];
        emitT += wsE[b * NC + c];
        q = qn;
    }

    float v = q * Eend;
#pragma unroll
    for (int m = 16; m >= 1; m >>= 1) v += __shfl_xor(v, m, 32);
    float fwd = __logf(v) + (float)Cq * 0.69314718055994531f;

    if (lane == 0) atomicAdd(out, fwd - emitT - tgold);
}

extern "C" void kernel_launch(void* const* d_in, const int* in_sizes, int n_in,
                              void* d_out, int out_size, void* d_ws, size_t ws_size,
                              hipStream_t stream)
{
    const float* emission    = (const float*)d_in[0];
    const int*   label_ids   = (const int*)d_in[1];
    const float* transitions = (const float*)d_in[2];
    float* out = (float*)d_out;

    unsigned short* wsM = (unsigned short*)d_ws;               // 8,388,608 B
    int*   wsC = (int*)((char*)d_ws + (size_t)BB * NC * 1024 * 2);
    float* wsE = (float*)((char*)wsC + BB * NC * sizeof(int));

    hipMemsetAsync(out, 0, sizeof(float), stream);
    crf_chunk_kernel<<<BB * NC, 64, 0, stream>>>(emission, label_ids, transitions,
                                                 wsM, wsC, wsE);
    crf_combine_kernel<<<BB, 64, 0, stream>>>(label_ids, transitions,
                                              wsM, wsC, wsE, out);
}

// Round 5
// 161.562 us; speedup vs baseline: 2.8814x; 1.2376x over previous
//
#include <hip/hip_runtime.h>

// CRF loss: sum_b(forward_score[b] - gold_score[b]).  B=512, T=1024, L=32.
//
// R5: fused chunked matrix-product scan. One block per batch (1024 thr =
// 16 waves = 16 chunks of 64 steps). Each wave computes its chunk's 32x32
// product M_c = prod(D_t E) via 2 chained mfma_32x32x16_bf16 per step.
// - C/D -> B-operand fixup via v_permlane32_swap_b32 (gfx950): pair
//   (acc[i], acc[i+4]) -> one swap gives both B slot regs (8 ops, replaces
//   16 ds_bpermute + 16 cndmask). __has_builtin-guarded, bpermute fallback.
// - Renorm deferred 2 steps: sc at step s applies e_{s-2}; readlane chain
//   fully off the MFMA critical path. Exact 2^-e, last two e's un-applied.
// - M_c stored to LDS f32 (row stride 33 -> conflict-free); wave 0 does the
//   16-chunk matvec combine after one __syncthreads. Gold transition score
//   distributed across all 16 waves (global gathers of the 4KB L1-hot table).
// Grid 512 x 1024thr = 2 blocks/CU = 8 waves/SIMD. No workspace.

typedef float    f32x16 __attribute__((ext_vector_type(16)));
typedef short    s16x8  __attribute__((ext_vector_type(8)));
typedef unsigned u32x2  __attribute__((ext_vector_type(2)));

#define TT 1024
#define LL 32
#define BB 512
#define NC 16
#define CL 64
#define MS 33            // padded row stride (floats) for LDS M tiles

#if __has_builtin(__builtin_amdgcn_permlane32_swap)
#define HAVE_PLSWAP 1
#else
#define HAVE_PLSWAP 0
#endif

union Frag { s16x8 v; unsigned u[4]; };

// pack two f32 -> u32 of 2 bf16 (truncation), via v_perm
__device__ __forceinline__ unsigned pack_bf16(float lo, float hi) {
    return __builtin_amdgcn_perm(__float_as_uint(hi), __float_as_uint(lo), 0x07060302u);
}

__global__ __launch_bounds__(NC * 64, 8) void crf_fused_kernel(
    const float* __restrict__ emission,    // [B, T, L]
    const int*   __restrict__ label_ids,   // [B, T]
    const float* __restrict__ transitions, // [L, L]
    float*       __restrict__ out)         // [1], pre-zeroed
{
    __shared__ __align__(16) float shM[NC][32 * MS];   // 67,584 B
    __shared__ float shQ[2][64];
    __shared__ float emitArr[NC], tgArr[NC];
    __shared__ int   capArr[NC];

    const int tid  = threadIdx.x;
    const int w    = tid >> 6;          // wave id = chunk id
    const int lane = tid & 63;
    const int j    = lane & 31;         // state / A row / C-D col
    const int h    = lane >> 5;         // k-half
    const int b    = blockIdx.x;
    const int t0   = w * CL;

    const int*   labB = label_ids + b * TT + t0;
    const float* emB  = emission + ((size_t)b * TT + t0) * LL + j;

    // ---- gold transition partial for this chunk (global gathers, L1-hot) ----
    {
        int t  = t0 + lane;
        int l1 = labB[lane];
        int l0 = (t == 0) ? 0 : label_ids[b * TT + t - 1];
        float tg = transitions[(l1 << 5) + l0];
        if (t == TT - 1) tg += transitions[32 + l1];   // trans[END=1, last]
#pragma unroll
        for (int m = 32; m >= 1; m >>= 1) tg += __shfl_xor(tg, m, 64);
        if (lane == 0) tgArr[w] = tg;
    }

    // ---- E fragments: A0 needs E[j][8h+i], A1 needs E[j][16+8h+i] ----
    const float* trow = transitions + j * 32;
    float E0[8], E1[8];
#pragma unroll
    for (int i = 0; i < 8; ++i) {
        E0[i] = __expf(trow[8 * h + i]);
        E1[i] = __expf(trow[16 + 8 * h + i]);
    }

    // ---- B operands start as identity (bf16 1.0 = 0x3F80) ----
    Frag B0, B1;
#pragma unroll
    for (int i = 0; i < 8; ++i) {
        B0.v[i] = (short)((8 * h + i == j) ? 0x3F80 : 0);
        B1.v[i] = (short)((16 + 8 * h + i == j) ? 0x3F80 : 0);
    }

    f32x16 zc, acc;
#pragma unroll
    for (int i = 0; i < 16; ++i) zc[i] = 0.0f;

    float ring[8];
#pragma unroll
    for (int s = 0; s < 8; ++s) ring[s] = emB[s * LL];

    float sc = 1.0f;                    // pending 2^-e_{s-2}
    int   Cap = 0, ep1 = 0, ep2 = 0;    // e_{s-1}, e_{s-2}
    float emit = 0.0f;

#pragma unroll 8
    for (int s = 0; s < CL; ++s) {
        float feat = ring[s & 7];
        int   lab  = labB[s];
        emit += (j == lab) ? feat : 0.0f;
        float fs = __expf(feat) * sc;

        // A = (2^-e * D_t) E rows, bf16
        Frag A0, A1;
#pragma unroll
        for (int p = 0; p < 4; ++p) {
            A0.u[p] = pack_bf16(fs * E0[2 * p], fs * E0[2 * p + 1]);
            A1.u[p] = pack_bf16(fs * E1[2 * p], fs * E1[2 * p + 1]);
        }

        acc = __builtin_amdgcn_mfma_f32_32x32x16_bf16(A0.v, B0.v, zc, 0, 0, 0);
        acc = __builtin_amdgcn_mfma_f32_32x32x16_bf16(A1.v, B1.v, acc, 0, 0, 0);

        // renorm proxy: M[2][0] (reg 2, lane 0) — off critical path (deferred)
        int pb = __builtin_amdgcn_readlane(__float_as_int(acc[2]), 0);
        int e  = ((pb >> 23) & 0xff) - 127;
        sc = __int_as_float((127 - ep1) << 23);   // next step applies e_{s-1}
        Cap += e;
        ep2 = ep1; ep1 = e;

        // refill ring (clamped inside chunk)
        int nf = s + 8; nf = (nf < CL) ? nf : (CL - 1);
        ring[s & 7] = emB[nf * LL];

        // ---- C/D layout -> next B operand ----
#if HAVE_PLSWAP
        {
            u32x2 p0 = __builtin_amdgcn_permlane32_swap(__float_as_uint(acc[0]),  __float_as_uint(acc[4]),  false, false);
            u32x2 p1 = __builtin_amdgcn_permlane32_swap(__float_as_uint(acc[1]),  __float_as_uint(acc[5]),  false, false);
            u32x2 p2 = __builtin_amdgcn_permlane32_swap(__float_as_uint(acc[2]),  __float_as_uint(acc[6]),  false, false);
            u32x2 p3 = __builtin_amdgcn_permlane32_swap(__float_as_uint(acc[3]),  __float_as_uint(acc[7]),  false, false);
            B0.u[0] = pack_bf16(__uint_as_float(p0[0]), __uint_as_float(p1[0]));
            B0.u[1] = pack_bf16(__uint_as_float(p2[0]), __uint_as_float(p3[0]));
            B0.u[2] = pack_bf16(__uint_as_float(p0[1]), __uint_as_float(p1[1]));
            B0.u[3] = pack_bf16(__uint_as_float(p2[1]), __uint_as_float(p3[1]));
            u32x2 q0 = __builtin_amdgcn_permlane32_swap(__float_as_uint(acc[8]),  __float_as_uint(acc[12]), false, false);
            u32x2 q1 = __builtin_amdgcn_permlane32_swap(__float_as_uint(acc[9]),  __float_as_uint(acc[13]), false, false);
            u32x2 q2 = __builtin_amdgcn_permlane32_swap(__float_as_uint(acc[10]), __float_as_uint(acc[14]), false, false);
            u32x2 q3 = __builtin_amdgcn_permlane32_swap(__float_as_uint(acc[11]), __float_as_uint(acc[15]), false, false);
            B1.u[0] = pack_bf16(__uint_as_float(q0[0]), __uint_as_float(q1[0]));
            B1.u[1] = pack_bf16(__uint_as_float(q2[0]), __uint_as_float(q3[0]));
            B1.u[2] = pack_bf16(__uint_as_float(q0[1]), __uint_as_float(q1[1]));
            B1.u[3] = pack_bf16(__uint_as_float(q2[1]), __uint_as_float(q3[1]));
        }
#else
        {
            const int swaddr = (lane ^ 32) << 2;
            float sw[16];
#pragma unroll
            for (int r = 0; r < 16; ++r)
                sw[r] = __int_as_float(
                    __builtin_amdgcn_ds_bpermute(swaddr, __float_as_int(acc[r])));
            float b0v[8], b1v[8];
#pragma unroll
            for (int i = 0; i < 4; ++i) {
                b0v[i]     = h ? sw[4 + i]   : acc[i];
                b0v[4 + i] = h ? acc[4 + i]  : sw[i];
                b1v[i]     = h ? sw[12 + i]  : acc[8 + i];
                b1v[4 + i] = h ? acc[12 + i] : sw[8 + i];
            }
#pragma unroll
            for (int p = 0; p < 4; ++p) {
                B0.u[p] = pack_bf16(b0v[2 * p], b0v[2 * p + 1]);
                B1.u[p] = pack_bf16(b1v[2 * p], b1v[2 * p + 1]);
            }
        }
#endif
    }
    Cap -= (ep1 + ep2);                 // last two e's never applied

    // ---- store M_c to LDS (f32, padded stride -> conflict-free) ----
#pragma unroll
    for (int r = 0; r < 16; ++r) {
        int row = (r & 3) + 8 * (r >> 2) + 4 * h;
        shM[w][row * MS + j] = acc[r];
    }
#pragma unroll
    for (int m = 16; m >= 1; m >>= 1) emit += __shfl_xor(emit, m, 32);
    if (lane == 0) { emitArr[w] = emit; capArr[w] = Cap; }

    __syncthreads();

    // ---- wave 0: sequential 16-chunk matvec combine ----
    if (w == 0) {
        const float Eend = __expf(transitions[32 + j]);   // exp(trans[END][j])
        float q = (j == 0) ? 1.0f : 0.0f;
        int   Cq = 0;
        float emitT = 0.0f;

#pragma unroll
        for (int c = 0; c < NC; ++c) {
            shQ[c & 1][lane] = q;
            asm volatile("s_waitcnt lgkmcnt(0)" ::: "memory");
            __builtin_amdgcn_wave_barrier();
            const float* Mrow = &shM[c][j * MS];
            const float* qv   = &shQ[c & 1][h * 32];
            float a0 = 0.f, a1 = 0.f, a2 = 0.f, a3 = 0.f;
#pragma unroll
            for (int i = 0; i < 32; i += 4) {
                a0 = fmaf(Mrow[i],     qv[i],     a0);
                a1 = fmaf(Mrow[i + 1], qv[i + 1], a1);
                a2 = fmaf(Mrow[i + 2], qv[i + 2], a2);
                a3 = fmaf(Mrow[i + 3], qv[i + 3], a3);
            }
            float qn = (a0 + a1) + (a2 + a3);
            int pb = __builtin_amdgcn_readlane(__float_as_int(qn), 2);
            int e  = ((pb >> 23) & 0xff) - 127;
            qn *= __int_as_float((127 - e) << 23);        // exact 2^-e
            Cq += e + capArr[c];
            emitT += emitArr[c];
            q = qn;
        }

        float v = q * Eend;
#pragma unroll
        for (int m = 16; m >= 1; m >>= 1) v += __shfl_xor(v, m, 32);
        float fwd = __logf(v) + (float)Cq * 0.69314718055994531f;

        float tgold = 0.0f;
#pragma unroll
        for (int c = 0; c < NC; ++c) tgold += tgArr[c];

        if (lane == 0) atomicAdd(out, fwd - emitT - tgold);
    }
}

extern "C" void kernel_launch(void* const* d_in, const int* in_sizes, int n_in,
                              void* d_out, int out_size, void* d_ws, size_t ws_size,
                              hipStream_t stream)
{
    const float* emission    = (const float*)d_in[0];
    const int*   label_ids   = (const int*)d_in[1];
    const float* transitions = (const float*)d_in[2];
    float* out = (float*)d_out;

    hipMemsetAsync(out, 0, sizeof(float), stream);
    crf_fused_kernel<<<BB, NC * 64, 0, stream>>>(emission, label_ids, transitions, out);
}

// Round 6
// 137.520 us; speedup vs baseline: 3.3852x; 1.1748x over previous
//
#include <hip/hip_runtime.h>

// CRF loss: sum_b(forward_score[b] - gold_score[b]).  B=512, T=1024, L=32.
//
// R6: fused chunked matrix-product scan, de-bloated.
// - One block per batch: 512 thr = 8 waves = 8 chunks of 128 steps; each wave
//   computes M_c = prod(D_t E) via 2 chained mfma_32x32x16_bf16 per step.
// - NO per-step cross-lane fixup: B is fed from acc regs directly
//   (B0.v[i]=acc[i], B1.v[i]=acc[8+i]; k=8h+i -> row (i&3)+8(i>>2)+4h is a
//   bijection sigma of 0..31) and E's columns are statically permuted by the
//   same sigma, so sum_k A[m,sigma(k)] M[sigma(k),n] is the true product.
// - __launch_bounds__(512,4): 128-VGPR budget, everything stays in arch
//   VGPRs (R5's (1024,8) forced a 32/32 VGPR/AGPR split -> accvgpr-move
//   bloat, the real reason VALUBusy was 67% at 285 cyc/step).
// - Renorm every 4 steps (growth <= ~2^52 << f32 range), exact 2^-e applied
//   on the group-start step only; last measured e un-applied (Cap -= elast).
// - Gold (trans + emission) gathered entirely in the preamble.
// - M_c -> LDS f32 (stride 33, conflict-free); wave 0 combines 8 chunks.
// Grid 512 x 512thr = 2 blocks/CU, 4 waves/SIMD, no workspace.

typedef float  f32x16 __attribute__((ext_vector_type(16)));
typedef short  s16x8  __attribute__((ext_vector_type(8)));

#define TT 1024
#define LL 32
#define BB 512
#define NC 8
#define CL 128
#define MS 33

union Frag { s16x8 v; unsigned u[4]; };

// pack two f32 -> u32 holding 2 bf16 (truncation): lo in [15:0], hi in [31:16]
__device__ __forceinline__ unsigned pack_bf16(float lo, float hi) {
    return __builtin_amdgcn_perm(__float_as_uint(hi), __float_as_uint(lo), 0x07060302u);
}

__global__ __launch_bounds__(NC * 64, 4) void crf_fused_kernel(
    const float* __restrict__ emission,    // [B, T, L]
    const int*   __restrict__ label_ids,   // [B, T]
    const float* __restrict__ transitions, // [L, L]
    float*       __restrict__ out)         // [1], pre-zeroed
{
    __shared__ __align__(16) float shM[NC][32 * MS];   // 33,792 B
    __shared__ float shQ[2][64];
    __shared__ float tgArr[NC];            // gold trans+emit partial per chunk
    __shared__ int   capArr[NC];

    const int tid  = threadIdx.x;
    const int w    = tid >> 6;             // wave id = chunk id
    const int lane = tid & 63;
    const int j    = lane & 31;            // A row m / C-D col n
    const int h    = lane >> 5;            // k-half
    const int b    = blockIdx.x;
    const int t0   = w * CL;

    const int*   labB = label_ids + b * TT + t0;
    const float* emB  = emission + ((size_t)b * TT + t0) * LL + j;

    // ---- gold score partial (transitions + emission gather), preamble ----
    {
        float g = 0.0f;
#pragma unroll
        for (int u = 0; u < 2; ++u) {
            int tt = t0 + 64 * u + lane;
            int l1 = labB[64 * u + lane];
            int l0 = (tt == 0) ? 0 : label_ids[b * TT + tt - 1];   // SOS at -1
            g += transitions[(l1 << 5) + l0];
            g += emission[((size_t)b * TT + tt) * LL + l1];
            if (tt == TT - 1) g += transitions[32 + l1];           // trans[END,last]
        }
#pragma unroll
        for (int m = 32; m >= 1; m >>= 1) g += __shfl_xor(g, m, 64);
        if (lane == 0) tgArr[w] = g;
    }

    // ---- E with sigma-permuted columns: E0'[i] = E[j][(i&3)+8(i>>2)+4h] ----
    const float* trow = transitions + j * 32;
    float E0[8], E1[8];
#pragma unroll
    for (int i = 0; i < 8; ++i) {
        int col = (i & 3) + 8 * (i >> 2) + 4 * h;
        E0[i] = __expf(trow[col]);
        E1[i] = __expf(trow[16 + col]);
    }

    // ---- B = identity in sigma layout (bf16 1.0 = 0x3F80) ----
    Frag B0, B1;
#pragma unroll
    for (int i = 0; i < 8; ++i) {
        int row = (i & 3) + 8 * (i >> 2) + 4 * h;
        B0.v[i] = (short)((row == j)      ? 0x3F80 : 0);
        B1.v[i] = (short)((row + 16 == j) ? 0x3F80 : 0);
    }

    f32x16 zc, acc;
#pragma unroll
    for (int i = 0; i < 16; ++i) zc[i] = 0.0f;

    float ring[8];
#pragma unroll
    for (int s = 0; s < 8; ++s) ring[s] = emB[s * LL];

    float sc = 1.0f;                       // pending 2^-e (applied group-start)
    int   Cap = 0, elast = 0;

    for (int s0 = 0; s0 < CL; s0 += 8) {
#pragma unroll
        for (int k = 0; k < 8; ++k) {
            const int s = s0 + k;
            float feat = ring[k];

            // scale applied only on group-start steps (k&3)==0
            float fs = ((k & 3) == 0) ? (__expf(feat) * sc) : __expf(feat);

            // A = (D_t E) rows in sigma column order, bf16
            Frag A0, A1;
#pragma unroll
            for (int p = 0; p < 4; ++p) {
                A0.u[p] = pack_bf16(fs * E0[2 * p], fs * E0[2 * p + 1]);
                A1.u[p] = pack_bf16(fs * E1[2 * p], fs * E1[2 * p + 1]);
            }

            acc = __builtin_amdgcn_mfma_f32_32x32x16_bf16(A0.v, B0.v, zc, 0, 0, 0);
            acc = __builtin_amdgcn_mfma_f32_32x32x16_bf16(A1.v, B1.v, acc, 0, 0, 0);

            // group-end: measure exponent proxy M[2][0] (reg 2, lane 0)
            if ((k & 3) == 3) {
                int pb = __builtin_amdgcn_readlane(__float_as_int(acc[2]), 0);
                int e  = ((pb >> 23) & 0xff) - 127;
                sc = __int_as_float((127 - e) << 23);     // exact 2^-e
                Cap += e;
                elast = e;
            }

            // refill ring (clamped inside chunk)
            int nf = s + 8; nf = (nf < CL) ? nf : (CL - 1);
            ring[k] = emB[nf * LL];

            // next B operand: direct reg feed (sigma layout), pack only
#pragma unroll
            for (int p = 0; p < 4; ++p) {
                B0.u[p] = pack_bf16(acc[2 * p],     acc[2 * p + 1]);
                B1.u[p] = pack_bf16(acc[8 + 2 * p], acc[9 + 2 * p]);
            }
        }
    }
    Cap -= elast;                          // final measured e never applied

    // ---- store M_c to LDS (f32, padded stride -> conflict-free) ----
#pragma unroll
    for (int r = 0; r < 16; ++r) {
        int row = (r & 3) + 8 * (r >> 2) + 4 * h;
        shM[w][row * MS + j] = acc[r];
    }
    if (lane == 0) capArr[w] = Cap;

    __syncthreads();

    // ---- wave 0: sequential 8-chunk matvec combine ----
    if (w == 0) {
        const float Eend = __expf(transitions[32 + j]);   // exp(trans[END][j])
        float q = (j == 0) ? 1.0f : 0.0f;                 // one-hot SOS
        int   Cq = 0;
        float gold = 0.0f;

#pragma unroll
        for (int c = 0; c < NC; ++c) {
            shQ[c & 1][lane] = q;
            asm volatile("s_waitcnt lgkmcnt(0)" ::: "memory");
            __builtin_amdgcn_wave_barrier();
            const float* Mrow = &shM[c][j * MS];
            const float* qv   = &shQ[c & 1][h * 32];
            float a0 = 0.f, a1 = 0.f, a2 = 0.f, a3 = 0.f;
#pragma unroll
            for (int i = 0; i < 32; i += 4) {
                a0 = fmaf(Mrow[i],     qv[i],     a0);
                a1 = fmaf(Mrow[i + 1], qv[i + 1], a1);
                a2 = fmaf(Mrow[i + 2], qv[i + 2], a2);
                a3 = fmaf(Mrow[i + 3], qv[i + 3], a3);
            }
            float qn = (a0 + a1) + (a2 + a3);
            int pb = __builtin_amdgcn_readlane(__float_as_int(qn), 2);
            int e  = ((pb >> 23) & 0xff) - 127;
            qn *= __int_as_float((127 - e) << 23);        // exact 2^-e
            Cq += e + capArr[c];
            gold += tgArr[c];
            q = qn;
        }

        float v = q * Eend;
#pragma unroll
        for (int m = 16; m >= 1; m >>= 1) v += __shfl_xor(v, m, 32);
        float fwd = __logf(v) + (float)Cq * 0.69314718055994531f;

        if (lane == 0) atomicAdd(out, fwd - gold);
    }
}

extern "C" void kernel_launch(void* const* d_in, const int* in_sizes, int n_in,
                              void* d_out, int out_size, void* d_ws, size_t ws_size,
                              hipStream_t stream)
{
    const float* emission    = (const float*)d_in[0];
    const int*   label_ids   = (const int*)d_in[1];
    const float* transitions = (const float*)d_in[2];
    float* out = (float*)d_out;

    hipMemsetAsync(out, 0, sizeof(float), stream);
    crf_fused_kernel<<<BB, NC * 64, 0, stream>>>(emission, label_ids, transitions, out);
}